// Round 14
// baseline (184.350 us; speedup 1.0000x reference)
//
#include <hip/hip_runtime.h>
#include <hip/hip_bf16.h>

typedef __attribute__((ext_vector_type(4))) float f32x4;
typedef __attribute__((ext_vector_type(8))) short s16x8;
typedef __attribute__((ext_vector_type(4))) short s16x4;

static constexpr int Bn = 32;
static constexpr int Tn = 4096;
static constexpr int Dn = 256;
static constexpr int Un = 256;
static constexpr int CH = Tn / 64;     // 64-row chunks per batch
static constexpr int NP = CH * 4;      // partials per batch (4 waves per chunk)

// HW bf16 cast (RTNE)
__device__ __forceinline__ ushort f2bf_hw(float f) {
    union { __hip_bfloat16 h; ushort u; } c;
    c.h = __float2bfloat16(f);
    return c.u;
}
__device__ __forceinline__ float bf2f(ushort u) {
    return __uint_as_float(((unsigned)u) << 16);
}
// 6-inst tanh: 1 - 2/(1+e^{2x})
__device__ __forceinline__ float tanh5(float x) {
    float t = __expf(2.0f * x);
    return 1.0f - __fdividef(2.0f, 1.0f + t);
}

// K0: prep. Blocks 0..255: W1T[u][d] = bf16(W1[d][u]). Blocks 256..287: qproj.
__global__ __launch_bounds__(256) void k_prep(const float* __restrict__ W1,
                                              ushort* __restrict__ W1T,
                                              const float* __restrict__ query,
                                              const float* __restrict__ W2,
                                              const float* __restrict__ b1,
                                              const float* __restrict__ b2,
                                              float* __restrict__ qb) {
    __shared__ float qs[Dn];
    if (blockIdx.x < 256) {
        const int u = blockIdx.x, d = threadIdx.x;
        W1T[u * Dn + d] = f2bf_hw(W1[d * Un + u]);
    } else {
        const int b = blockIdx.x - 256, u = threadIdx.x;
        qs[u] = query[b * Dn + u];
        __syncthreads();
        float acc = b1[u] + b2[u];
        #pragma unroll 8
        for (int d = 0; d < Dn; ++d) acc += qs[d] * W2[d * Un + u];
        qb[b * Un + u] = acc;
    }
}

// K1: FREE-RUNNING WAVES — zero __syncthreads. Each wave autonomously:
// stages its own 16 rows (private LDS segment, wave-local lgkmcnt ordering),
// k-loop with af from private LDS + B global->reg quarter-kc ring (16KB/kc
// working set = L1-hot; trailing waves draft leaders), wave-local epilogue
// (tanh·V, 16-lane reduce, flash m/S/p via private slp), wave-local context
// partial, own global partial write. Convoy broken: waves interleave stalls.
__global__ __launch_bounds__(256, 4) void k_free(const float* __restrict__ values,
                                                 const ushort* __restrict__ W1T,
                                                 const float* __restrict__ qb,
                                                 const float* __restrict__ Vw,
                                                 const float* __restrict__ bV,
                                                 float* __restrict__ scores,
                                                 float* __restrict__ pm,
                                                 float* __restrict__ ps,
                                                 float* __restrict__ pctx) {
    __shared__ __align__(16) ushort Al[4][16][264];   // 33.8 KB, wave-private segments
    __shared__ float slp[4][16];                      // wave-private score/p slots
    const int tid = threadIdx.x;
    const int b = blockIdx.y, c = blockIdx.x;
    const int wid = tid >> 6, lane = tid & 63;
    const int l15 = lane & 15, hi = lane >> 4;
    const int t0 = c * 64 + wid * 16;

    // ---- wave-private stage: 16 rows x 256 d, fp32 -> bf16 -> private LDS ----
    const float* vbase = values + ((size_t)b * Tn + t0) * Dn;
    #pragma unroll
    for (int j = 0; j < 8; ++j) {
        int flat = j * 512 + lane * 8;     // 512 floats = 2 rows per sweep
        int row = flat >> 8, col = flat & 255;
        const float4 f0 = *(const float4*)&vbase[row * Dn + col];
        const float4 f1 = *(const float4*)&vbase[row * Dn + col + 4];
        s16x8 p;
        p[0] = (short)f2bf_hw(f0.x); p[1] = (short)f2bf_hw(f0.y);
        p[2] = (short)f2bf_hw(f0.z); p[3] = (short)f2bf_hw(f0.w);
        p[4] = (short)f2bf_hw(f1.x); p[5] = (short)f2bf_hw(f1.y);
        p[6] = (short)f2bf_hw(f1.z); p[7] = (short)f2bf_hw(f1.w);
        *(s16x8*)&Al[wid][row][col] = p;
    }
    // no barrier: af reads below are same-wave, ordered by lgkmcnt

    f32x4 acc[16];
    #pragma unroll
    for (int ut = 0; ut < 16; ++ut) acc[ut] = (f32x4){0.f, 0.f, 0.f, 0.f};

    // B quarter-kc pipeline, depth-1; af double-buffered across kc
    const ushort* wb = W1T + (size_t)l15 * Dn + hi * 8;  // + ut*16*Dn + kc*32
    s16x8 bq[4], bn[4];
    #pragma unroll
    for (int j = 0; j < 4; ++j)
        bq[j] = *(const s16x8*)&wb[(size_t)j * 16 * Dn];

    s16x8 afc = *(const s16x8*)&Al[wid][l15][hi * 8];
    s16x8 afn;

    #pragma unroll
    for (int kc = 0; kc < 8; ++kc) {
        if (kc < 7) afn = *(const s16x8*)&Al[wid][l15][(kc + 1) * 32 + hi * 8];
        #pragma unroll
        for (int q = 0; q < 4; ++q) {
            const int nk = (q == 3) ? kc + 1 : kc;
            const int nq = (q + 1) & 3;
            if (!(kc == 7 && q == 3)) {
                #pragma unroll
                for (int j = 0; j < 4; ++j)
                    bn[j] = *(const s16x8*)&wb[(size_t)(nq * 4 + j) * 16 * Dn + nk * 32];
            }
            #pragma unroll
            for (int j = 0; j < 4; ++j)
                acc[q * 4 + j] = __builtin_amdgcn_mfma_f32_16x16x32_bf16(afc, bq[j], acc[q * 4 + j], 0, 0, 0);
            #pragma unroll
            for (int j = 0; j < 4; ++j) bq[j] = bn[j];
        }
        afc = afn;
    }

    // ---- wave-local epilogue: tanh·V, reduce over 16 u-lanes ----
    float psc[4] = {0.f, 0.f, 0.f, 0.f};
    #pragma unroll
    for (int ut = 0; ut < 16; ++ut) {
        const int u = ut * 16 + l15;
        const float Vv = Vw[u];
        const float qv = qb[b * Un + u];
        #pragma unroll
        for (int i = 0; i < 4; ++i)
            psc[i] += tanh5(acc[ut][i] + qv) * Vv;
    }
    #pragma unroll
    for (int i = 0; i < 4; ++i) {
        float v = psc[i];
        v += __shfl_xor(v, 1, 64);
        v += __shfl_xor(v, 2, 64);
        v += __shfl_xor(v, 4, 64);
        v += __shfl_xor(v, 8, 64);
        psc[i] = v;                       // valid on l15 == 0
    }
    const float bv = bV[0];
    if (l15 == 0) {
        #pragma unroll
        for (int i = 0; i < 4; ++i) slp[wid][hi * 4 + i] = psc[i] + bv;
    }
    // wave-local flash over the 16 scores (lgkmcnt orders the slp ops)
    float sr = slp[wid][l15];
    if (hi == 0) scores[b * Tn + t0 + l15] = sr;
    float m = sr;
    m = fmaxf(m, __shfl_xor(m, 1, 64));
    m = fmaxf(m, __shfl_xor(m, 2, 64));
    m = fmaxf(m, __shfl_xor(m, 4, 64));
    m = fmaxf(m, __shfl_xor(m, 8, 64));
    const float p = __expf(sr - m);
    float S = p;
    S += __shfl_xor(S, 1, 64);
    S += __shfl_xor(S, 2, 64);
    S += __shfl_xor(S, 4, 64);
    S += __shfl_xor(S, 8, 64);
    if (hi == 0) slp[wid][l15] = p;

    // ---- wave-local context partial from private bf16 rows ----
    const int d4 = lane * 4;
    f32x4 loc = (f32x4){0.f, 0.f, 0.f, 0.f};
    #pragma unroll
    for (int t = 0; t < 16; ++t) {
        const float pk = slp[wid][t];     // uniform address -> broadcast
        const s16x4 v = *(const s16x4*)&Al[wid][t][d4];
        loc[0] += pk * bf2f((ushort)v[0]);
        loc[1] += pk * bf2f((ushort)v[1]);
        loc[2] += pk * bf2f((ushort)v[2]);
        loc[3] += pk * bf2f((ushort)v[3]);
    }
    const int pp = (b * CH + c) * 4 + wid;
    *(f32x4*)&pctx[(size_t)pp * Dn + d4] = loc;
    if (lane == 0) { pm[pp] = m; ps[pp] = S; }
}

// K2: per-batch flash reduce over NP wave partials.
__global__ __launch_bounds__(256) void k_reduce(const float* __restrict__ pm,
                                                const float* __restrict__ ps,
                                                const float* __restrict__ pctx,
                                                float* __restrict__ context,
                                                float* __restrict__ MS) {
    const int b = blockIdx.x, d = threadIdx.x;
    float M = -1e30f;
    #pragma unroll 8
    for (int c = 0; c < NP; ++c) M = fmaxf(M, pm[b * NP + c]);
    float S = 0.f, ctx = 0.f;
    #pragma unroll 4
    for (int c = 0; c < NP; ++c) {
        const float w = __expf(pm[b * NP + c] - M);
        S += w * ps[b * NP + c];
        ctx += w * pctx[((size_t)(b * NP + c)) * Dn + d];
    }
    context[b * Dn + d] = __fdividef(ctx, S);
    if (d == 0) { MS[b * 2] = M; MS[b * 2 + 1] = S; }
}

// K3: attn[b,t] = exp(score - M_b) / S_b, in place.
__global__ __launch_bounds__(256) void k_attn(float* __restrict__ attn,
                                              const float* __restrict__ MS) {
    const int b = blockIdx.y;
    const int base = b * Tn + blockIdx.x * 1024 + threadIdx.x * 4;
    const float M = MS[b * 2];
    const float invS = __fdividef(1.0f, MS[b * 2 + 1]);
    float4 s = *(const float4*)&attn[base];
    s.x = __expf(s.x - M) * invS;
    s.y = __expf(s.y - M) * invS;
    s.z = __expf(s.z - M) * invS;
    s.w = __expf(s.w - M) * invS;
    *(float4*)&attn[base] = s;
}

extern "C" void kernel_launch(void* const* d_in, const int* in_sizes, int n_in,
                              void* d_out, int out_size, void* d_ws, size_t ws_size,
                              hipStream_t stream) {
    const float* query  = (const float*)d_in[0];
    const float* values = (const float*)d_in[1];
    const float* W1     = (const float*)d_in[2];
    const float* b1     = (const float*)d_in[3];
    const float* W2     = (const float*)d_in[4];
    const float* b2     = (const float*)d_in[5];
    const float* Vw     = (const float*)d_in[6];
    const float* bV     = (const float*)d_in[7];

    float* context = (float*)d_out;            // [B,D]
    float* attn    = (float*)d_out + Bn * Dn;  // [B,T,1] — raw scores, then attn in place

    float*  pctx = (float*)d_ws;                       // [B, NP, D] = 8 MB
    float*  pm   = pctx + (size_t)Bn * NP * Dn;        // [B, NP]
    float*  ps   = pm + Bn * NP;                       // [B, NP]
    float*  qb   = ps + Bn * NP;                       // [B, U]
    float*  MS   = qb + Bn * Un;                       // [B, 2]
    ushort* W1T  = (ushort*)(MS + Bn * 2);             // [U, D] bf16

    k_prep<<<dim3(256 + Bn), dim3(256), 0, stream>>>(W1, W1T, query, W2, b1, b2, qb);
    k_free<<<dim3(CH, Bn), dim3(256), 0, stream>>>(values, W1T, qb, Vw, bV,
                                                   attn, pm, ps, pctx);
    k_reduce<<<dim3(Bn), dim3(256), 0, stream>>>(pm, ps, pctx, context, MS);
    k_attn<<<dim3(Tn / 1024, Bn), dim3(256), 0, stream>>>(attn, MS);
}

// Round 15
// 77.219 us; speedup vs baseline: 2.3874x; 2.3874x over previous
//
#include <hip/hip_runtime.h>
#include <hip/hip_bf16.h>

typedef __attribute__((ext_vector_type(4))) float f32x4;
typedef __attribute__((ext_vector_type(8))) short s16x8;
typedef __attribute__((ext_vector_type(4))) short s16x4;

static constexpr int Bn = 32;
static constexpr int Tn = 4096;
static constexpr int Dn = 256;
static constexpr int Un = 256;
static constexpr int CH = Tn / 64;   // 64 chunks per batch, 1 chunk per block

// HW bf16 cast (RTNE)
__device__ __forceinline__ ushort f2bf_hw(float f) {
    union { __hip_bfloat16 h; ushort u; } c;
    c.h = __float2bfloat16(f);
    return c.u;
}
__device__ __forceinline__ float bf2f(ushort u) {
    return __uint_as_float(((unsigned)u) << 16);
}
// 6-inst tanh: 1 - 2/(1+e^{2x})
__device__ __forceinline__ float tanh5(float x) {
    float t = __expf(2.0f * x);
    return 1.0f - __fdividef(2.0f, 1.0f + t);
}

// K0a: fragment-major W1 for coalesced MFMA A-operand loads.
// Fragment f = (wc*4 + ut)*8 + kc (128 total). Element (f, lane, j):
//   u = wc*64 + ut*16 + (lane&15), d = kc*32 + (lane>>4)*8 + j.
// In-kernel load: one 16B/lane read of 64 consecutive lanes = 1KB segment.
__global__ __launch_bounds__(256) void k_w1f(const float* __restrict__ W1,
                                             ushort* __restrict__ W1F) {
    const int g = blockIdx.x * 256 + threadIdx.x;   // 8192 = 128 frags x 64 lanes
    const int f = g >> 6, lane = g & 63;
    const int kc = f & 7, ut = (f >> 3) & 3, wc = f >> 5;
    const int u = wc * 64 + ut * 16 + (lane & 15);
    const int d0 = kc * 32 + (lane >> 4) * 8;
    s16x8 p;
    #pragma unroll
    for (int j = 0; j < 8; ++j)
        p[j] = (short)f2bf_hw(W1[(size_t)(d0 + j) * Un + u]);
    *(s16x8*)&W1F[(size_t)g * 8] = p;
}

// K0b: qb[b][u] = query[b]·W2[:,u] + b1[u] + b2[u]
__global__ __launch_bounds__(256) void k_qproj(const float* __restrict__ query,
                                               const float* __restrict__ W2,
                                               const float* __restrict__ b1,
                                               const float* __restrict__ b2,
                                               float* __restrict__ qb) {
    __shared__ float qs[Dn];
    const int b = blockIdx.x, u = threadIdx.x;
    qs[u] = query[b * Dn + u];
    __syncthreads();
    float acc = b1[u] + b2[u];
    #pragma unroll 8
    for (int d = 0; d < Dn; ++d) acc += qs[d] * W2[d * Un + u];
    qb[b * Un + u] = acc;
}

// K1: R11 skeleton + swapped MFMA operands + fragment-major B.
// mfma(a=W1frag, b=valuesfrag): acc[ut][tt] lane(l15,hi) reg i =
//   proj[u = wid*64+ut*16+hi*4+i][t = t0+tt*16+l15]  -> u is IN-LANE:
// tanh·V dot accumulates 16 terms locally, cross-lane reduce = 2 shfls/tt
// (was 4 shfls x 16 values). W1F loads are fully coalesced (1KB/instr).
__global__ __launch_bounds__(256, 4) void k_fused(const float* __restrict__ values,
                                                  const ushort* __restrict__ W1F,
                                                  const float* __restrict__ qb,
                                                  const float* __restrict__ Vw,
                                                  const float* __restrict__ bV,
                                                  float* __restrict__ scores,
                                                  float* __restrict__ pm,
                                                  float* __restrict__ ps,
                                                  float* __restrict__ pctx) {
    __shared__ __align__(16) ushort Al[64][264];   // 33.8 KB, 528B rows (2-way free)
    __shared__ float sred[4][64];                  // 1 KB
    __shared__ f32x4 cred[4][64];                  // 4 KB
    const int tid = threadIdx.x;
    const int b = blockIdx.y, c = blockIdx.x;
    const int t0 = c * 64;
    const int wid = tid >> 6, lane = tid & 63;
    const int l15 = lane & 15, hi = lane >> 4;

    // stage A (values): 64 rows x 256 d, fp32 coalesced -> bf16 -> LDS
    const float* vbase = values + ((size_t)b * Tn + t0) * Dn;
    #pragma unroll
    for (int i = 0; i < 8; ++i) {
        int flat = i * 2048 + tid * 8;
        int row = flat >> 8, col = flat & 255;
        const float4 f0 = *(const float4*)&vbase[row * Dn + col];
        const float4 f1 = *(const float4*)&vbase[row * Dn + col + 4];
        s16x8 p;
        p[0] = (short)f2bf_hw(f0.x); p[1] = (short)f2bf_hw(f0.y);
        p[2] = (short)f2bf_hw(f0.z); p[3] = (short)f2bf_hw(f0.w);
        p[4] = (short)f2bf_hw(f1.x); p[5] = (short)f2bf_hw(f1.y);
        p[6] = (short)f2bf_hw(f1.z); p[7] = (short)f2bf_hw(f1.w);
        *(s16x8*)&Al[row][col] = p;
    }

    // this wave's W1F slice: 32 frags of 1KB, frag index (ut*8 + kc)
    const ushort* wf = W1F + (size_t)wid * 32 * 512 + lane * 8;

    f32x4 acc[4][4];   // [ut][tt]
    #pragma unroll
    for (int ut = 0; ut < 4; ++ut)
        #pragma unroll
        for (int tt = 0; tt < 4; ++tt) acc[ut][tt] = (f32x4){0.f, 0.f, 0.f, 0.f};

    // W1F prefetch depth 1 (coalesced)
    s16x8 wcur[4], wnxt[4];
    #pragma unroll
    for (int ut = 0; ut < 4; ++ut)
        wcur[ut] = *(const s16x8*)&wf[(size_t)(ut * 8) * 512];

    __syncthreads();  // B1: A tile ready

    #pragma unroll
    for (int kc = 0; kc < 8; ++kc) {
        if (kc < 7) {
            #pragma unroll
            for (int ut = 0; ut < 4; ++ut)
                wnxt[ut] = *(const s16x8*)&wf[(size_t)(ut * 8 + kc + 1) * 512];
        }
        const int k0 = kc * 32;
        s16x8 af[4];
        #pragma unroll
        for (int tt = 0; tt < 4; ++tt)
            af[tt] = *(const s16x8*)&Al[tt * 16 + l15][k0 + hi * 8];
        #pragma unroll
        for (int ut = 0; ut < 4; ++ut)
            #pragma unroll
            for (int tt = 0; tt < 4; ++tt)
                acc[ut][tt] = __builtin_amdgcn_mfma_f32_16x16x32_bf16(wcur[ut], af[tt], acc[ut][tt], 0, 0, 0);
        if (kc < 7) {
            #pragma unroll
            for (int ut = 0; ut < 4; ++ut) wcur[ut] = wnxt[ut];
        }
    }

    // epilogue constants: this lane's 16 u-values = wid*64 + ut*16 + hi*4 + i
    float4 Vq[4], qq[4];
    #pragma unroll
    for (int ut = 0; ut < 4; ++ut) {
        const int u0 = wid * 64 + ut * 16 + hi * 4;
        Vq[ut] = *(const float4*)&Vw[u0];
        qq[ut] = *(const float4*)&qb[b * Un + u0];
    }

    // u is in-lane: accumulate 16 tanh·V terms locally, then 2 shfls per tt
    #pragma unroll
    for (int tt = 0; tt < 4; ++tt) {
        float v = 0.f;
        #pragma unroll
        for (int ut = 0; ut < 4; ++ut) {
            v += tanh5(acc[ut][tt][0] + qq[ut].x) * Vq[ut].x;
            v += tanh5(acc[ut][tt][1] + qq[ut].y) * Vq[ut].y;
            v += tanh5(acc[ut][tt][2] + qq[ut].z) * Vq[ut].z;
            v += tanh5(acc[ut][tt][3] + qq[ut].w) * Vq[ut].w;
        }
        v += __shfl_xor(v, 16, 64);
        v += __shfl_xor(v, 32, 64);
        if (hi == 0) sred[wid][tt * 16 + l15] = v;
    }
    __syncthreads();  // B2: sred ready

    // redundant wave-parallel flash over 64 rows (row = lane)
    float s = sred[0][lane] + sred[1][lane] + sred[2][lane] + sred[3][lane] + bV[0];
    if (wid == 0) scores[b * Tn + t0 + lane] = s;
    float m = s;
    #pragma unroll
    for (int off = 32; off > 0; off >>= 1) m = fmaxf(m, __shfl_xor(m, off, 64));
    const float p = __expf(s - m);
    float S = p;
    #pragma unroll
    for (int off = 32; off > 0; off >>= 1) S += __shfl_xor(S, off, 64);

    // context partial from bf16 tile; p[t] via intra-wave broadcast shuffle
    const int d4 = lane * 4;
    f32x4 loc = (f32x4){0.f, 0.f, 0.f, 0.f};
    #pragma unroll
    for (int k = 0; k < 16; ++k) {
        const int t = wid + 4 * k;
        const float pk = __shfl(p, t, 64);
        const s16x4 v = *(const s16x4*)&Al[t][d4];
        loc[0] += pk * bf2f((ushort)v[0]);
        loc[1] += pk * bf2f((ushort)v[1]);
        loc[2] += pk * bf2f((ushort)v[2]);
        loc[3] += pk * bf2f((ushort)v[3]);
    }
    cred[wid][lane] = loc;
    __syncthreads();  // B3: cred ready
    if (wid == 0) {
        const f32x4 o = cred[0][lane] + cred[1][lane] + cred[2][lane] + cred[3][lane];
        *(f32x4*)&pctx[((size_t)(b * CH + c)) * Dn + d4] = o;
    }
    if (tid == 0) { pm[b * CH + c] = m; ps[b * CH + c] = S; }
}

// K2: per-batch flash reduce over CH chunk partials.
__global__ __launch_bounds__(256) void k_reduce(const float* __restrict__ pm,
                                                const float* __restrict__ ps,
                                                const float* __restrict__ pctx,
                                                float* __restrict__ context,
                                                float* __restrict__ MS) {
    const int b = blockIdx.x, d = threadIdx.x;
    float M = -1e30f;
    #pragma unroll 8
    for (int c = 0; c < CH; ++c) M = fmaxf(M, pm[b * CH + c]);
    float S = 0.f, ctx = 0.f;
    #pragma unroll 4
    for (int c = 0; c < CH; ++c) {
        const float w = __expf(pm[b * CH + c] - M);
        S += w * ps[b * CH + c];
        ctx += w * pctx[((size_t)(b * CH + c)) * Dn + d];
    }
    context[b * Dn + d] = __fdividef(ctx, S);
    if (d == 0) { MS[b * 2] = M; MS[b * 2 + 1] = S; }
}

// K3: attn[b,t] = exp(score - M_b) / S_b, in place.
__global__ __launch_bounds__(256) void k_attn(float* __restrict__ attn,
                                              const float* __restrict__ MS) {
    const int b = blockIdx.y;
    const int base = b * Tn + blockIdx.x * 1024 + threadIdx.x * 4;
    const float M = MS[b * 2];
    const float invS = __fdividef(1.0f, MS[b * 2 + 1]);
    float4 s = *(const float4*)&attn[base];
    s.x = __expf(s.x - M) * invS;
    s.y = __expf(s.y - M) * invS;
    s.z = __expf(s.z - M) * invS;
    s.w = __expf(s.w - M) * invS;
    *(float4*)&attn[base] = s;
}

extern "C" void kernel_launch(void* const* d_in, const int* in_sizes, int n_in,
                              void* d_out, int out_size, void* d_ws, size_t ws_size,
                              hipStream_t stream) {
    const float* query  = (const float*)d_in[0];
    const float* values = (const float*)d_in[1];
    const float* W1     = (const float*)d_in[2];
    const float* b1     = (const float*)d_in[3];
    const float* W2     = (const float*)d_in[4];
    const float* b2     = (const float*)d_in[5];
    const float* Vw     = (const float*)d_in[6];
    const float* bV     = (const float*)d_in[7];

    float* context = (float*)d_out;            // [B,D]
    float* attn    = (float*)d_out + Bn * Dn;  // [B,T,1] — raw scores, then attn in place

    float*  pctx = (float*)d_ws;                       // [B, CH, D] = 2 MB
    float*  pm   = pctx + (size_t)Bn * CH * Dn;        // [B, CH]
    float*  ps   = pm + Bn * CH;                       // [B, CH]
    float*  qb   = ps + Bn * CH;                       // [B, U]
    float*  MS   = qb + Bn * Un;                       // [B, 2]
    ushort* W1F  = (ushort*)(MS + Bn * 2);             // fragment-major W1, 128 KB

    k_w1f<<<dim3(32), dim3(256), 0, stream>>>(W1, W1F);
    k_qproj<<<dim3(Bn), dim3(256), 0, stream>>>(query, W2, b1, b2, qb);
    k_fused<<<dim3(CH, Bn), dim3(256), 0, stream>>>(values, W1F, qb, Vw, bV,
                                                    attn, pm, ps, pctx);
    k_reduce<<<dim3(Bn), dim3(256), 0, stream>>>(pm, ps, pctx, context, MS);
    k_attn<<<dim3(Tn / 1024, Bn), dim3(256), 0, stream>>>(attn, MS);
}